// Round 1
// baseline (867.100 us; speedup 1.0000x reference)
//
#include <hip/hip_runtime.h>
#include <hip/hip_bf16.h>
#include <math.h>

#define NN 50000
#define NE 800000
#define FIN 256
#define FOUT 32
#define NH 8
#define FE 5
#define AROW 69          // 2*FOUT + FE
#define CCOLS 256        // NH*FOUT

// ---------------- W transpose: W[h][f][o] -> Wt[f][h*32+o] ----------------
__global__ __launch_bounds__(256) void k_transposeW(const float* __restrict__ W,
                                                    float* __restrict__ Wt) {
    int idx = blockIdx.x * 256 + threadIdx.x;      // 0..65535
    int f = idx >> 8, c = idx & 255;
    int h = c >> 5, o = c & 31;
    Wt[idx] = W[h * (FIN * FOUT) + f * FOUT + o];
}

// ---------------- C[h][k] = sum_j a_e[h][j] * Wew[j][k] ----------------
__global__ void k_cmat(const float* __restrict__ a, const float* __restrict__ Wew,
                       float* __restrict__ C) {
    int t = threadIdx.x;
    if (t < NH * FE) {
        int h = t / FE, k = t % FE;
        float s = 0.f;
        for (int j = 0; j < FE; ++j) s += a[h * AROW + 2 * FOUT + j] * Wew[j * FE + k];
        C[t] = s;
    }
}

// ---------------- GEMM: Wh[n][c] = sum_f x[n][f] * Wt[f][c] ----------------
// block tile 64 rows x 256 cols, 256 threads, 8x8 per-thread fragment
__global__ __launch_bounds__(256) void k_gemm(const float* __restrict__ x,
                                              const float* __restrict__ Wt,
                                              float* __restrict__ Wh, int nrows) {
    __shared__ float At[32 * 68];    // [k][r], padded stride 68
    __shared__ float Bt[32 * 256];   // [k][c]
    int t = threadIdx.x;
    int ty = t >> 5, tx = t & 31;
    int row0 = blockIdx.x * 64;
    float acc[8][8];
#pragma unroll
    for (int i = 0; i < 8; ++i)
#pragma unroll
        for (int j = 0; j < 8; ++j) acc[i][j] = 0.f;

    for (int k0 = 0; k0 < FIN; k0 += 32) {
        // stage A: 64 rows x 32 k (transposed into LDS)
#pragma unroll
        for (int ii = 0; ii < 2; ++ii) {
            int idx = t + ii * 256;          // 0..511
            int r = idx >> 3, kq = idx & 7;
            float4 v = make_float4(0.f, 0.f, 0.f, 0.f);
            int row = row0 + r;
            if (row < nrows) v = *(const float4*)&x[(size_t)row * FIN + k0 + kq * 4];
            At[(kq * 4 + 0) * 68 + r] = v.x;
            At[(kq * 4 + 1) * 68 + r] = v.y;
            At[(kq * 4 + 2) * 68 + r] = v.z;
            At[(kq * 4 + 3) * 68 + r] = v.w;
        }
        // stage B: 32 k x 256 c
#pragma unroll
        for (int ii = 0; ii < 8; ++ii) {
            int idx = t + ii * 256;          // 0..2047
            int k = idx >> 6, c4 = idx & 63;
            *(float4*)&Bt[k * 256 + c4 * 4] =
                *(const float4*)&Wt[(size_t)(k0 + k) * 256 + c4 * 4];
        }
        __syncthreads();
#pragma unroll
        for (int k = 0; k < 32; ++k) {
            float4 a0 = *(const float4*)&At[k * 68 + ty * 8];
            float4 a1 = *(const float4*)&At[k * 68 + ty * 8 + 4];
            float4 b0 = *(const float4*)&Bt[k * 256 + tx * 8];
            float4 b1 = *(const float4*)&Bt[k * 256 + tx * 8 + 4];
            float av[8] = {a0.x, a0.y, a0.z, a0.w, a1.x, a1.y, a1.z, a1.w};
            float bv[8] = {b0.x, b0.y, b0.z, b0.w, b1.x, b1.y, b1.z, b1.w};
#pragma unroll
            for (int i = 0; i < 8; ++i)
#pragma unroll
                for (int j = 0; j < 8; ++j) acc[i][j] += av[i] * bv[j];
        }
        __syncthreads();
    }
#pragma unroll
    for (int i = 0; i < 8; ++i) {
        int row = row0 + ty * 8 + i;
        if (row < nrows) {
            *(float4*)&Wh[(size_t)row * 256 + tx * 8] =
                make_float4(acc[i][0], acc[i][1], acc[i][2], acc[i][3]);
            *(float4*)&Wh[(size_t)row * 256 + tx * 8 + 4] =
                make_float4(acc[i][4], acc[i][5], acc[i][6], acc[i][7]);
        }
    }
}

// ---------------- s1[n,h], s2[n,h] ----------------
__global__ __launch_bounds__(256) void k_s1s2(const float* __restrict__ Wh,
                                              const float* __restrict__ a,
                                              float* __restrict__ s1, float* __restrict__ s2) {
    int i = blockIdx.x * 256 + threadIdx.x;    // i = n*8 + h
    if (i >= NN * NH) return;
    int h = i & 7;
    const float* w = &Wh[(size_t)i * 32];      // Wh[n][h][:] contiguous
    float d1 = 0.f, d2 = 0.f;
#pragma unroll
    for (int o = 0; o < 32; ++o) {
        float v = w[o];
        d1 += v * a[h * AROW + o];
        d2 += v * a[h * AROW + FOUT + o];
    }
    s1[i] = d1;
    s2[i] = d2;
}

// ---------------- edge logits + leaky_relu + scale + segmax + counts ----------------
__global__ __launch_bounds__(256) void k_edge(const int* __restrict__ ei,
                                              const float* __restrict__ eattr,
                                              const int* __restrict__ degs,
                                              const float* __restrict__ s1,
                                              const float* __restrict__ s2,
                                              const float* __restrict__ C,
                                              float* __restrict__ e_buf,
                                              unsigned int* __restrict__ emax,
                                              int* __restrict__ counts) {
    __shared__ float Cl[NH * FE];
    int t = threadIdx.x;
    if (t < NH * FE) Cl[t] = C[t];
    __syncthreads();
    int e = blockIdx.x * 256 + t;
    if (e >= NE) return;
    int src = ei[e], dst = ei[NE + e];
    int dg = degs[e];
    float scale = rsqrtf((float)(dg > 1 ? dg : 1));
    float ea0 = eattr[(size_t)e * FE + 0];
    float ea1 = eattr[(size_t)e * FE + 1];
    float ea2 = eattr[(size_t)e * FE + 2];
    float ea3 = eattr[(size_t)e * FE + 3];
    float ea4 = eattr[(size_t)e * FE + 4];
    int sb = src * NH, db = dst * NH;
#pragma unroll
    for (int h = 0; h < NH; ++h) {
        float v = s1[sb + h] + s2[db + h] + ea0 * Cl[h * FE + 0] + ea1 * Cl[h * FE + 1] +
                  ea2 * Cl[h * FE + 2] + ea3 * Cl[h * FE + 3] + ea4 * Cl[h * FE + 4];
        v = v > 0.f ? v : 0.2f * v;
        v *= scale;
        e_buf[(size_t)e * NH + h] = v;
        if (v > 0.f) atomicMax(&emax[sb + h], __float_as_uint(v));
    }
    atomicAdd(&counts[src], 1);
}

// ---------------- scan (3-level) ----------------
__global__ __launch_bounds__(256) void k_scanA(const int* __restrict__ counts,
                                               int* __restrict__ part,
                                               int* __restrict__ bsums, int n) {
    __shared__ int lds[256];
    int t = threadIdx.x;
    int base = blockIdx.x * 1024;
    int i0 = base + t * 4;
    int v0 = (i0 + 0 < n) ? counts[i0 + 0] : 0;
    int v1 = (i0 + 1 < n) ? counts[i0 + 1] : 0;
    int v2 = (i0 + 2 < n) ? counts[i0 + 2] : 0;
    int v3 = (i0 + 3 < n) ? counts[i0 + 3] : 0;
    int l0 = v0, l1 = l0 + v1, l2 = l1 + v2, l3 = l2 + v3;
    lds[t] = l3;
    __syncthreads();
    for (int off = 1; off < 256; off <<= 1) {
        int val = lds[t];
        if (t >= off) val += lds[t - off];
        __syncthreads();
        lds[t] = val;
        __syncthreads();
    }
    int excl = (t == 0) ? 0 : lds[t - 1];
    if (i0 + 0 < n) part[i0 + 0] = excl;
    if (i0 + 1 < n) part[i0 + 1] = excl + l0;
    if (i0 + 2 < n) part[i0 + 2] = excl + l1;
    if (i0 + 3 < n) part[i0 + 3] = excl + l2;
    if (t == 255) bsums[blockIdx.x] = lds[255];
}

__global__ void k_scanB(const int* __restrict__ bsums, int* __restrict__ boffs, int nb) {
    if (threadIdx.x == 0) {
        int run = 0;
        for (int b = 0; b < nb; ++b) { boffs[b] = run; run += bsums[b]; }
    }
}

__global__ __launch_bounds__(256) void k_scanC(int* __restrict__ row_ptr,
                                               const int* __restrict__ boffs, int n, int total) {
    int i = blockIdx.x * 256 + threadIdx.x;
    if (i < n) row_ptr[i] += boffs[i >> 10];
    else if (i == n) row_ptr[n] = total;
}

// ---------------- scatter edges into CSR order ----------------
__global__ __launch_bounds__(256) void k_scatter(const int* __restrict__ ei,
                                                 const int* __restrict__ row_ptr,
                                                 int* __restrict__ fill,
                                                 int* __restrict__ pos,
                                                 int* __restrict__ dst_perm) {
    int e = blockIdx.x * 256 + threadIdx.x;
    if (e >= NE) return;
    int src = ei[e];
    int p = row_ptr[src] + atomicAdd(&fill[src], 1);
    pos[e] = p;
    dst_perm[p] = ei[NE + e];
}

// ---------------- exp + segment-sum ----------------
__global__ __launch_bounds__(256) void k_exp(const int* __restrict__ ei,
                                             float* __restrict__ e_buf,
                                             const unsigned int* __restrict__ emax,
                                             float* __restrict__ esum) {
    int e = blockIdx.x * 256 + threadIdx.x;
    if (e >= NE) return;
    int sb = ei[e] * NH;
#pragma unroll
    for (int h = 0; h < NH; ++h) {
        float v = e_buf[(size_t)e * NH + h];
        float m = __uint_as_float(emax[sb + h]);
        float ex = expf(v - m);
        e_buf[(size_t)e * NH + h] = ex;
        atomicAdd(&esum[sb + h], ex);
    }
}

// ---------------- alpha + permuted alpha ----------------
__global__ __launch_bounds__(256) void k_alpha(const int* __restrict__ ei,
                                               const float* __restrict__ e_buf,
                                               const float* __restrict__ esum,
                                               const int* __restrict__ pos,
                                               float* __restrict__ out_alpha,
                                               float* __restrict__ alpha_perm) {
    int e = blockIdx.x * 256 + threadIdx.x;
    if (e >= NE) return;
    int sb = ei[e] * NH;
    int p = pos[e];
#pragma unroll
    for (int h = 0; h < NH; ++h) {
        float al = e_buf[(size_t)e * NH + h] / (esum[sb + h] + 1e-16f);
        out_alpha[(size_t)e * NH + h] = al;
        alpha_perm[(size_t)p * NH + h] = al;
    }
}

// ---------------- message aggregation + ELU, one block per node ----------------
__global__ __launch_bounds__(256) void k_msg(const int* __restrict__ row_ptr,
                                             const int* __restrict__ dst_perm,
                                             const float* __restrict__ alpha_perm,
                                             const float* __restrict__ Wh,
                                             float* __restrict__ out) {
    __shared__ int dl[32];
    __shared__ float al[256];
    int n = blockIdx.x;
    int t = threadIdx.x;
    int h = t >> 5;
    int start = row_ptr[n], end = row_ptr[n + 1];
    float acc = 0.f;
    for (int base = start; base < end; base += 32) {
        int cnt = end - base;
        if (cnt > 32) cnt = 32;
        if (t < cnt) dl[t] = dst_perm[base + t];
        if (t < cnt * 8) al[t] = alpha_perm[(size_t)base * 8 + t];
        __syncthreads();
        for (int j = 0; j < cnt; ++j) {
            acc += al[j * 8 + h] * Wh[(size_t)dl[j] * 256 + t];
        }
        __syncthreads();
    }
    float o = acc > 0.f ? acc : expm1f(acc);
    out[(size_t)n * 256 + t] = o;
}

extern "C" void kernel_launch(void* const* d_in, const int* in_sizes, int n_in,
                              void* d_out, int out_size, void* d_ws, size_t ws_size,
                              hipStream_t stream) {
    const float* x     = (const float*)d_in[0];
    const int*   ei    = (const int*)d_in[1];     // [2][E]
    const float* eattr = (const float*)d_in[2];   // [E][5]
    const int*   degs  = (const int*)d_in[3];     // [E]
    const float* W     = (const float*)d_in[4];   // [8][256][32]
    const float* a     = (const float*)d_in[5];   // [8][69]
    const float* Wew   = (const float*)d_in[6];   // [5][5]

    float* out       = (float*)d_out;                    // N*256
    float* out_alpha = out + (size_t)NN * 256;           // E*8

    // bump allocator over d_ws
    char* p = (char*)d_ws;
    auto alloc = [&](size_t bytes) -> char* {
        char* r = p;
        p += (bytes + 255) & ~(size_t)255;
        return r;
    };
    float*        Wh         = (float*)alloc((size_t)NN * 256 * 4);
    float*        s1         = (float*)alloc((size_t)NN * NH * 4);
    float*        s2         = (float*)alloc((size_t)NN * NH * 4);
    float*        e_buf      = (float*)alloc((size_t)NE * NH * 4);
    unsigned int* emax       = (unsigned int*)alloc((size_t)NN * NH * 4);
    float*        esum       = (float*)alloc((size_t)NN * NH * 4);
    float*        Wt         = (float*)alloc((size_t)256 * 256 * 4);
    float*        Cm         = (float*)alloc(NH * FE * 4);
    int*          counts     = (int*)alloc((size_t)NN * 4);
    int*          row_ptr    = (int*)alloc((size_t)(NN + 1) * 4);
    int*          fill       = (int*)alloc((size_t)NN * 4);
    int*          bsums      = (int*)alloc(64 * 4);
    int*          boffs      = (int*)alloc(64 * 4);
    int*          pos        = (int*)alloc((size_t)NE * 4);
    int*          dst_perm   = (int*)alloc((size_t)NE * 4);
    float*        alpha_perm = (float*)alloc((size_t)NE * NH * 4);

    // zero-init accumulators (every call — ws persists between replays)
    hipMemsetAsync(emax, 0, (size_t)NN * NH * 4, stream);
    hipMemsetAsync(esum, 0, (size_t)NN * NH * 4, stream);
    hipMemsetAsync(counts, 0, (size_t)NN * 4, stream);
    hipMemsetAsync(fill, 0, (size_t)NN * 4, stream);

    k_transposeW<<<256, 256, 0, stream>>>(W, Wt);
    k_cmat<<<1, 64, 0, stream>>>(a, Wew, Cm);
    k_gemm<<<(NN + 63) / 64, 256, 0, stream>>>(x, Wt, Wh, NN);
    k_s1s2<<<(NN * NH + 255) / 256, 256, 0, stream>>>(Wh, a, s1, s2);
    k_edge<<<(NE + 255) / 256, 256, 0, stream>>>(ei, eattr, degs, s1, s2, Cm, e_buf, emax, counts);
    k_scanA<<<(NN + 1023) / 1024, 256, 0, stream>>>(counts, row_ptr, bsums, NN);
    k_scanB<<<1, 64, 0, stream>>>(bsums, boffs, (NN + 1023) / 1024);
    k_scanC<<<(NN + 1 + 255) / 256, 256, 0, stream>>>(row_ptr, boffs, NN, NE);
    k_scatter<<<(NE + 255) / 256, 256, 0, stream>>>(ei, row_ptr, fill, pos, dst_perm);
    k_exp<<<(NE + 255) / 256, 256, 0, stream>>>(ei, e_buf, emax, esum);
    k_alpha<<<(NE + 255) / 256, 256, 0, stream>>>(ei, e_buf, esum, pos, out_alpha, alpha_perm);
    k_msg<<<NN, 256, 0, stream>>>(row_ptr, dst_perm, alpha_perm, Wh, out);
}

// Round 2
// 412.703 us; speedup vs baseline: 2.1010x; 2.1010x over previous
//
#include <hip/hip_runtime.h>
#include <hip/hip_bf16.h>
#include <math.h>

#define NN 50000
#define NE 800000
#define FIN 256
#define FOUT 32
#define NH 8
#define FE 5
#define AROW 69          // 2*FOUT + FE

// ---------------- C[h][k] = sum_j a_e[h][j] * Wew[j][k] ----------------
__global__ void k_cmat(const float* __restrict__ a, const float* __restrict__ Wew,
                       float* __restrict__ C) {
    int t = threadIdx.x;
    if (t < NH * FE) {
        int h = t / FE, k = t % FE;
        float s = 0.f;
        for (int j = 0; j < FE; ++j) s += a[h * AROW + 2 * FOUT + j] * Wew[j * FE + k];
        C[t] = s;
    }
}

// ---------------- GEMM: Wh[n][c] = sum_f x[n][f] * W[h][f][o], c=h*32+o ------
// block tile 64 rows x 256 cols, 256 threads, 8x8 per-thread fragment.
// Fused epilogue: s1[n,h] = <Wh[n,h,:], a_src[h]>, s2 likewise with a_dst.
__global__ __launch_bounds__(256) void k_gemm(const float* __restrict__ x,
                                              const float* __restrict__ W,
                                              const float* __restrict__ a,
                                              float* __restrict__ Wh,
                                              float* __restrict__ s1,
                                              float* __restrict__ s2, int nrows) {
    __shared__ float At[32 * 68];    // [k][r], padded stride 68
    __shared__ float Bt[32 * 256];   // [k][c]
    int t = threadIdx.x;
    int ty = t >> 5, tx = t & 31;
    int row0 = blockIdx.x * 64;
    float acc[8][8];
#pragma unroll
    for (int i = 0; i < 8; ++i)
#pragma unroll
        for (int j = 0; j < 8; ++j) acc[i][j] = 0.f;

    for (int k0 = 0; k0 < FIN; k0 += 32) {
        // stage A: 64 rows x 32 k (transposed into LDS)
#pragma unroll
        for (int ii = 0; ii < 2; ++ii) {
            int idx = t + ii * 256;          // 0..511
            int r = idx >> 3, kq = idx & 7;
            float4 v = make_float4(0.f, 0.f, 0.f, 0.f);
            int row = row0 + r;
            if (row < nrows) v = *(const float4*)&x[(size_t)row * FIN + k0 + kq * 4];
            At[(kq * 4 + 0) * 68 + r] = v.x;
            At[(kq * 4 + 1) * 68 + r] = v.y;
            At[(kq * 4 + 2) * 68 + r] = v.z;
            At[(kq * 4 + 3) * 68 + r] = v.w;
        }
        // stage B: 32 k x 256 c, transposing W[h][f][o] on the fly
#pragma unroll
        for (int ii = 0; ii < 8; ++ii) {
            int idx = t + ii * 256;          // 0..2047
            int k = idx >> 6, c4 = idx & 63;  // c = c4*4
            int h = c4 >> 3, o = (c4 * 4) & 31;
            *(float4*)&Bt[k * 256 + c4 * 4] =
                *(const float4*)&W[(size_t)h * (FIN * FOUT) + (size_t)(k0 + k) * FOUT + o];
        }
        __syncthreads();
#pragma unroll
        for (int k = 0; k < 32; ++k) {
            float4 a0 = *(const float4*)&At[k * 68 + ty * 8];
            float4 a1 = *(const float4*)&At[k * 68 + ty * 8 + 4];
            float4 b0 = *(const float4*)&Bt[k * 256 + tx * 8];
            float4 b1 = *(const float4*)&Bt[k * 256 + tx * 8 + 4];
            float av[8] = {a0.x, a0.y, a0.z, a0.w, a1.x, a1.y, a1.z, a1.w};
            float bv[8] = {b0.x, b0.y, b0.z, b0.w, b1.x, b1.y, b1.z, b1.w};
#pragma unroll
            for (int i = 0; i < 8; ++i)
#pragma unroll
                for (int j = 0; j < 8; ++j) acc[i][j] += av[i] * bv[j];
        }
        __syncthreads();
    }
    // write Wh
#pragma unroll
    for (int i = 0; i < 8; ++i) {
        int row = row0 + ty * 8 + i;
        if (row < nrows) {
            *(float4*)&Wh[(size_t)row * 256 + tx * 8] =
                make_float4(acc[i][0], acc[i][1], acc[i][2], acc[i][3]);
            *(float4*)&Wh[(size_t)row * 256 + tx * 8 + 4] =
                make_float4(acc[i][4], acc[i][5], acc[i][6], acc[i][7]);
        }
    }
    // fused s1/s2: head h = tx>>2; this thread's 8 cols = a[h][(tx&3)*8 .. +8)
    int h = tx >> 2;
    float as_r[8], ad_r[8];
    const float* ap = &a[h * AROW + (tx & 3) * 8];
#pragma unroll
    for (int j = 0; j < 8; ++j) { as_r[j] = ap[j]; ad_r[j] = ap[FOUT + j]; }
#pragma unroll
    for (int i = 0; i < 8; ++i) {
        float p1 = 0.f, p2 = 0.f;
#pragma unroll
        for (int j = 0; j < 8; ++j) {
            p1 += acc[i][j] * as_r[j];
            p2 += acc[i][j] * ad_r[j];
        }
        p1 += __shfl_xor(p1, 1); p1 += __shfl_xor(p1, 2);
        p2 += __shfl_xor(p2, 1); p2 += __shfl_xor(p2, 2);
        int row = row0 + ty * 8 + i;
        if ((tx & 3) == 0 && row < nrows) {
            s1[row * NH + h] = p1;
            s2[row * NH + h] = p2;
        }
    }
}

// ---------------- counts ----------------
__global__ __launch_bounds__(256) void k_count(const int* __restrict__ ei,
                                               int* __restrict__ counts) {
    int e = blockIdx.x * 256 + threadIdx.x;
    if (e < NE) atomicAdd(&counts[ei[e]], 1);
}

// ---------------- scan (3-level) ----------------
__global__ __launch_bounds__(256) void k_scanA(const int* __restrict__ counts,
                                               int* __restrict__ part,
                                               int* __restrict__ bsums, int n) {
    __shared__ int lds[256];
    int t = threadIdx.x;
    int base = blockIdx.x * 1024;
    int i0 = base + t * 4;
    int v0 = (i0 + 0 < n) ? counts[i0 + 0] : 0;
    int v1 = (i0 + 1 < n) ? counts[i0 + 1] : 0;
    int v2 = (i0 + 2 < n) ? counts[i0 + 2] : 0;
    int v3 = (i0 + 3 < n) ? counts[i0 + 3] : 0;
    int l0 = v0, l1 = l0 + v1, l2 = l1 + v2, l3 = l2 + v3;
    lds[t] = l3;
    __syncthreads();
    for (int off = 1; off < 256; off <<= 1) {
        int val = lds[t];
        if (t >= off) val += lds[t - off];
        __syncthreads();
        lds[t] = val;
        __syncthreads();
    }
    int excl = (t == 0) ? 0 : lds[t - 1];
    if (i0 + 0 < n) part[i0 + 0] = excl;
    if (i0 + 1 < n) part[i0 + 1] = excl + l0;
    if (i0 + 2 < n) part[i0 + 2] = excl + l1;
    if (i0 + 3 < n) part[i0 + 3] = excl + l2;
    if (t == 255) bsums[blockIdx.x] = lds[255];
}

__global__ void k_scanB(const int* __restrict__ bsums, int* __restrict__ boffs, int nb) {
    if (threadIdx.x == 0) {
        int run = 0;
        for (int b = 0; b < nb; ++b) { boffs[b] = run; run += bsums[b]; }
    }
}

__global__ __launch_bounds__(256) void k_scanC(int* __restrict__ row_ptr,
                                               const int* __restrict__ boffs, int n, int total) {
    int i = blockIdx.x * 256 + threadIdx.x;
    if (i < n) row_ptr[i] += boffs[i >> 10];
    else if (i == n) row_ptr[n] = total;
}

// ------- scatter + logits: compute e[h], write permuted; no fp atomics -------
__global__ __launch_bounds__(256) void k_scatlog(const int* __restrict__ ei,
                                                 const float* __restrict__ eattr,
                                                 const int* __restrict__ degs,
                                                 const float* __restrict__ s1,
                                                 const float* __restrict__ s2,
                                                 const float* __restrict__ C,
                                                 const int* __restrict__ row_ptr,
                                                 int* __restrict__ fill,
                                                 float* __restrict__ e_perm,
                                                 int2* __restrict__ de_perm) {
    __shared__ float Cl[NH * FE];
    int t = threadIdx.x;
    if (t < NH * FE) Cl[t] = C[t];
    __syncthreads();
    int e = blockIdx.x * 256 + t;
    if (e >= NE) return;
    int src = ei[e], dst = ei[NE + e];
    int dg = degs[e];
    float scale = rsqrtf((float)(dg > 1 ? dg : 1));
    float ea0 = eattr[(size_t)e * FE + 0];
    float ea1 = eattr[(size_t)e * FE + 1];
    float ea2 = eattr[(size_t)e * FE + 2];
    float ea3 = eattr[(size_t)e * FE + 3];
    float ea4 = eattr[(size_t)e * FE + 4];
    float4 s1a = *(const float4*)&s1[src * NH];
    float4 s1b = *(const float4*)&s1[src * NH + 4];
    float4 s2a = *(const float4*)&s2[dst * NH];
    float4 s2b = *(const float4*)&s2[dst * NH + 4];
    float vs1[8] = {s1a.x, s1a.y, s1a.z, s1a.w, s1b.x, s1b.y, s1b.z, s1b.w};
    float vs2[8] = {s2a.x, s2a.y, s2a.z, s2a.w, s2b.x, s2b.y, s2b.z, s2b.w};
    float v[8];
#pragma unroll
    for (int h = 0; h < NH; ++h) {
        float q = vs1[h] + vs2[h] + ea0 * Cl[h * FE + 0] + ea1 * Cl[h * FE + 1] +
                  ea2 * Cl[h * FE + 2] + ea3 * Cl[h * FE + 3] + ea4 * Cl[h * FE + 4];
        q = q > 0.f ? q : 0.2f * q;
        v[h] = q * scale;
    }
    int p = row_ptr[src] + atomicAdd(&fill[src], 1);
    *(float4*)&e_perm[(size_t)p * 8]     = make_float4(v[0], v[1], v[2], v[3]);
    *(float4*)&e_perm[(size_t)p * 8 + 4] = make_float4(v[4], v[5], v[6], v[7]);
    de_perm[p] = make_int2(dst, e);
}

// ------- per-node softmax: one wave per node, shuffle reductions -------
__global__ __launch_bounds__(256) void k_softmax(const int* __restrict__ row_ptr,
                                                 const float* __restrict__ e_perm,
                                                 const int2* __restrict__ de_perm,
                                                 float* __restrict__ alpha_perm,
                                                 float* __restrict__ out_alpha) {
    int t = threadIdx.x;
    int n = blockIdx.x * 4 + (t >> 6);
    if (n >= NN) return;
    int l = t & 63;
    int j = l >> 3, h = l & 7;
    int start = row_ptr[n], deg = row_ptr[n + 1] - start;
    if (deg == 0) return;
    // pass 1: max (clamped at 0)
    float m = 0.f;
    for (int base = 0; base < deg; base += 8) {
        int idx = base + j;
        if (idx < deg) m = fmaxf(m, e_perm[(size_t)(start + idx) * 8 + h]);
    }
    m = fmaxf(m, __shfl_xor(m, 8));
    m = fmaxf(m, __shfl_xor(m, 16));
    m = fmaxf(m, __shfl_xor(m, 32));
    // pass 2: sum of exp
    float s = 0.f;
    for (int base = 0; base < deg; base += 8) {
        int idx = base + j;
        if (idx < deg) s += __expf(e_perm[(size_t)(start + idx) * 8 + h] - m);
    }
    s += __shfl_xor(s, 8);
    s += __shfl_xor(s, 16);
    s += __shfl_xor(s, 32);
    float inv = 1.f / (s + 1e-16f);
    // pass 3: alpha
    for (int base = 0; base < deg; base += 8) {
        int idx = base + j;
        if (idx < deg) {
            size_t p = (size_t)(start + idx);
            float al = __expf(e_perm[p * 8 + h] - m) * inv;
            alpha_perm[p * 8 + h] = al;
            int eid = de_perm[p].y;
            out_alpha[(size_t)eid * 8 + h] = al;
        }
    }
}

// ---------------- message aggregation + ELU, one block per node ----------------
__global__ __launch_bounds__(256) void k_msg(const int* __restrict__ row_ptr,
                                             const int2* __restrict__ de_perm,
                                             const float* __restrict__ alpha_perm,
                                             const float* __restrict__ Wh,
                                             float* __restrict__ out) {
    __shared__ int dl[32];
    __shared__ float al[256];
    int n = blockIdx.x;
    int t = threadIdx.x;
    int h = t >> 5;
    int start = row_ptr[n], end = row_ptr[n + 1];
    float acc = 0.f;
    for (int base = start; base < end; base += 32) {
        int cnt = end - base;
        if (cnt > 32) cnt = 32;
        if (t < cnt) dl[t] = de_perm[base + t].x;
        if (t < cnt * 8) al[t] = alpha_perm[(size_t)base * 8 + t];
        __syncthreads();
        for (int jj = 0; jj < cnt; ++jj) {
            acc += al[jj * 8 + h] * Wh[(size_t)dl[jj] * 256 + t];
        }
        __syncthreads();
    }
    float o = acc > 0.f ? acc : expm1f(acc);
    out[(size_t)n * 256 + t] = o;
}

extern "C" void kernel_launch(void* const* d_in, const int* in_sizes, int n_in,
                              void* d_out, int out_size, void* d_ws, size_t ws_size,
                              hipStream_t stream) {
    const float* x     = (const float*)d_in[0];
    const int*   ei    = (const int*)d_in[1];     // [2][E]
    const float* eattr = (const float*)d_in[2];   // [E][5]
    const int*   degs  = (const int*)d_in[3];     // [E]
    const float* W     = (const float*)d_in[4];   // [8][256][32]
    const float* a     = (const float*)d_in[5];   // [8][69]
    const float* Wew   = (const float*)d_in[6];   // [5][5]

    float* out       = (float*)d_out;                    // N*256
    float* out_alpha = out + (size_t)NN * 256;           // E*8

    // bump allocator over d_ws
    char* p = (char*)d_ws;
    auto alloc = [&](size_t bytes) -> char* {
        char* r = p;
        p += (bytes + 255) & ~(size_t)255;
        return r;
    };
    float* Wh         = (float*)alloc((size_t)NN * 256 * 4);
    float* s1         = (float*)alloc((size_t)NN * NH * 4);
    float* s2         = (float*)alloc((size_t)NN * NH * 4);
    float* Cm         = (float*)alloc(NH * FE * 4);
    int*   counts     = (int*)alloc((size_t)NN * 4);
    int*   row_ptr    = (int*)alloc((size_t)(NN + 1) * 4);
    int*   fill       = (int*)alloc((size_t)NN * 4);
    int*   bsums      = (int*)alloc(64 * 4);
    int*   boffs      = (int*)alloc(64 * 4);
    float* e_perm     = (float*)alloc((size_t)NE * NH * 4);
    int2*  de_perm    = (int2*)alloc((size_t)NE * 8);
    float* alpha_perm = (float*)alloc((size_t)NE * NH * 4);

    hipMemsetAsync(counts, 0, (size_t)NN * 4, stream);
    hipMemsetAsync(fill, 0, (size_t)NN * 4, stream);

    k_cmat<<<1, 64, 0, stream>>>(a, Wew, Cm);
    k_gemm<<<(NN + 63) / 64, 256, 0, stream>>>(x, W, a, Wh, s1, s2, NN);
    k_count<<<(NE + 255) / 256, 256, 0, stream>>>(ei, counts);
    k_scanA<<<(NN + 1023) / 1024, 256, 0, stream>>>(counts, row_ptr, bsums, NN);
    k_scanB<<<1, 64, 0, stream>>>(bsums, boffs, (NN + 1023) / 1024);
    k_scanC<<<(NN + 1 + 255) / 256, 256, 0, stream>>>(row_ptr, boffs, NN, NE);
    k_scatlog<<<(NE + 255) / 256, 256, 0, stream>>>(ei, eattr, degs, s1, s2, Cm,
                                                    row_ptr, fill, e_perm, de_perm);
    k_softmax<<<(NN + 3) / 4, 256, 0, stream>>>(row_ptr, e_perm, de_perm,
                                                alpha_perm, out_alpha);
    k_msg<<<NN, 256, 0, stream>>>(row_ptr, de_perm, alpha_perm, Wh, out);
}